// Round 1
// 1299.735 us; speedup vs baseline: 1.9810x; 1.9810x over previous
//
#include <hip/hip_runtime.h>
#include <math.h>

// Problem constants (from reference)
#define T_WIN   3
#define N_NODES 50000
#define HID     128
#define E_PER_T 100000
#define NH      8
#define DK      16

// R5: ffn_kernel was 3x421us with MfmaUtil=0, VALUBusy=70% (fp32 VALU GEMM at
// ~31TF). FFN + projections moved to bf16 MFMA (projections use hi/lo split
// to keep fp32-equivalent precision). K/V projections cached when ws allows.

typedef unsigned short u16;
typedef __attribute__((ext_vector_type(8))) short bf16x8;   // 8 bf16 = 4 VGPR
typedef __attribute__((ext_vector_type(4))) float f32x4;

__device__ __forceinline__ u16 f2bf(float v) {              // RNE f32->bf16
    unsigned u = __float_as_uint(v);
    return (u16)((u + 0x7fffu + ((u >> 16) & 1u)) >> 16);
}
__device__ __forceinline__ float bf2f(u16 u) {
    return __uint_as_float(((unsigned)u) << 16);
}
__device__ __forceinline__ f32x4 mfma16(bf16x8 a, bf16x8 b, f32x4 c) {
    return __builtin_amdgcn_mfma_f32_16x16x32_bf16(a, b, c, 0, 0, 0);
}

// ---------------------------------------------------------------------------
// Weight prep: transposed bf16 copies. wsplit also emits the lo residual
// (hi = bf16(w), lo = bf16(w - hi)) for fp32-equivalent split-MFMA.
// dst layout: [C][R] (output-major, K contiguous) so B-fragments are 16B reads.
// ---------------------------------------------------------------------------
__global__ __launch_bounds__(256) void wsplit_kernel(
    const float* __restrict__ src, u16* __restrict__ hi, u16* __restrict__ lo,
    int R, int C)
{
    int i = blockIdx.x * 256 + threadIdx.x;
    if (i >= R * C) return;
    int r = i / C, c = i - r * C;
    float v = src[i];
    u16 h = f2bf(v);
    hi[c * R + r] = h;
    lo[c * R + r] = f2bf(v - bf2f(h));
}

__global__ __launch_bounds__(256) void wt_kernel(
    const float* __restrict__ src, u16* __restrict__ dst, int R, int C)
{
    int i = blockIdx.x * 256 + threadIdx.x;
    if (i >= R * C) return;
    int r = i / C, c = i - r * C;
    dst[c * R + r] = f2bf(src[i]);
}

// ---------------------------------------------------------------------------
// CSR build (once, before the t loop).
// ---------------------------------------------------------------------------
__global__ __launch_bounds__(256) void zero_counts_kernel(int* cursor)
{
    int i = blockIdx.x * 256 + threadIdx.x;
    if (i < T_WIN * N_NODES) cursor[i] = 0;
}

__global__ __launch_bounds__(256) void hist_kernel(
    const int* __restrict__ ei, int* counts)
{
    int i = blockIdx.x * 256 + threadIdx.x;
    if (i >= T_WIN * E_PER_T) return;
    int ts = i / E_PER_T;
    int e  = i - ts * E_PER_T;
    int tar = ei[(ts * 2 + 1) * E_PER_T + e];
    atomicAdd(&counts[ts * N_NODES + tar], 1);
}

__global__ __launch_bounds__(1024) void scan_kernel(
    const int* __restrict__ counts, int* __restrict__ offs)
{
    __shared__ int buf[1024];
    __shared__ int carry;
    const int ts = blockIdx.x;
    const int tid = threadIdx.x;
    if (tid == 0) carry = 0;
    __syncthreads();
    for (int base = 0; base < N_NODES; base += 1024) {
        int i = base + tid;
        int v = (i < N_NODES) ? counts[ts * N_NODES + i] : 0;
        buf[tid] = v;
        __syncthreads();
        for (int o = 1; o < 1024; o <<= 1) {
            int t = (tid >= o) ? buf[tid - o] : 0;
            __syncthreads();
            buf[tid] += t;
            __syncthreads();
        }
        int incl = buf[tid];
        if (i < N_NODES) offs[ts * (N_NODES + 1) + i] = carry + incl - v;
        __syncthreads();
        if (tid == 1023) carry += incl;
        __syncthreads();
    }
    if (tid == 0) offs[ts * (N_NODES + 1) + N_NODES] = carry;
}

__global__ __launch_bounds__(256) void copy_cursor_kernel(
    const int* __restrict__ offs, int* cursor)
{
    int i = blockIdx.x * 256 + threadIdx.x;
    if (i >= T_WIN * N_NODES) return;
    int ts = i / N_NODES;
    int n  = i - ts * N_NODES;
    cursor[i] = offs[ts * (N_NODES + 1) + n];
}

__global__ __launch_bounds__(256) void fill_kernel(
    const int* __restrict__ ei, int* cursor, int* __restrict__ eidbuf)
{
    int i = blockIdx.x * 256 + threadIdx.x;
    if (i >= T_WIN * E_PER_T) return;
    int ts = i / E_PER_T;
    int e  = i - ts * E_PER_T;
    int tar = ei[(ts * 2 + 1) * E_PER_T + e];
    int pos = atomicAdd(&cursor[ts * N_NODES + tar], 1);
    eidbuf[ts * E_PER_T + pos] = e;
}

// ---------------------------------------------------------------------------
// Split-bf16 MFMA projection: O[64 rows, 128] = x @ W + b, bf16 out.
// A staged as hi/lo bf16 in XOR-swizzled LDS (chunk = 8 elems = 16B,
// ch' = ch ^ (row&15) -> conflict-free ds_read_b128 fragments).
// 3 MFMA passes (ah*bh + ah*bl + al*bh) give fp32-equivalent precision.
// ---------------------------------------------------------------------------
__global__ __launch_bounds__(256) void project_mfma_kernel(
    const float* __restrict__ x, const u16* __restrict__ WTh,
    const u16* __restrict__ WTl, const float* __restrict__ b,
    u16* __restrict__ O)
{
    __shared__ u16 xhS[64 * 128];
    __shared__ u16 xlS[64 * 128];
    const int tid = threadIdx.x;
    const int n0 = blockIdx.x * 64;

    {   // stage: 4 threads/row, each covers 32 cols
        const int row = tid >> 2, q = tid & 3;
        const int n = n0 + row;
        const float4* xp = (const float4*)(x + (size_t)n * 128 + q * 32);
        const int sbase = row * 128;
#pragma unroll
        for (int i = 0; i < 4; ++i) {
            float4 a = make_float4(0.f, 0.f, 0.f, 0.f), c = a;
            if (n < N_NODES) { a = xp[2 * i]; c = xp[2 * i + 1]; }
            float vv[8] = {a.x, a.y, a.z, a.w, c.x, c.y, c.z, c.w};
            uint4 uh, ul;
            unsigned* ph = (unsigned*)&uh;
            unsigned* pl = (unsigned*)&ul;
#pragma unroll
            for (int j = 0; j < 4; ++j) {
                u16 h0 = f2bf(vv[2 * j]), h1 = f2bf(vv[2 * j + 1]);
                ph[j] = (unsigned)h0 | ((unsigned)h1 << 16);
                u16 l0 = f2bf(vv[2 * j] - bf2f(h0));
                u16 l1 = f2bf(vv[2 * j + 1] - bf2f(h1));
                pl[j] = (unsigned)l0 | ((unsigned)l1 << 16);
            }
            int ch = (q * 4 + i) ^ (row & 15);
            *(uint4*)&xhS[sbase + ch * 8] = uh;
            *(uint4*)&xlS[sbase + ch * 8] = ul;
        }
    }
    __syncthreads();

    const int lane = tid & 63, w = tid >> 6;
    const int l15 = lane & 15, l4 = lane >> 4;
    f32x4 acc[4][2];
    const f32x4 z4 = {0.f, 0.f, 0.f, 0.f};
#pragma unroll
    for (int m = 0; m < 4; ++m)
#pragma unroll
        for (int n = 0; n < 2; ++n) acc[m][n] = z4;

#pragma unroll
    for (int ks = 0; ks < 4; ++ks) {
        const int ch = (ks * 4 + l4) ^ l15;
        bf16x8 ah[4], al[4];
#pragma unroll
        for (int m = 0; m < 4; ++m) {
            ah[m] = *(const bf16x8*)&xhS[(m * 16 + l15) * 128 + ch * 8];
            al[m] = *(const bf16x8*)&xlS[(m * 16 + l15) * 128 + ch * 8];
        }
        bf16x8 bh[2], bl[2];
#pragma unroll
        for (int n = 0; n < 2; ++n) {
            size_t wo = (size_t)(w * 32 + n * 16 + l15) * 128 + ks * 32 + l4 * 8;
            bh[n] = *(const bf16x8*)(WTh + wo);
            bl[n] = *(const bf16x8*)(WTl + wo);
        }
#pragma unroll
        for (int m = 0; m < 4; ++m)
#pragma unroll
            for (int n = 0; n < 2; ++n) {
                acc[m][n] = mfma16(ah[m], bh[n], acc[m][n]);
                acc[m][n] = mfma16(ah[m], bl[n], acc[m][n]);
                acc[m][n] = mfma16(al[m], bh[n], acc[m][n]);
            }
    }

    // C/D: col = lane&15, row = (lane>>4)*4 + reg  [m89-verified]
#pragma unroll
    for (int n = 0; n < 2; ++n) {
        int c = w * 32 + n * 16 + l15;
        float bb = b[c];
#pragma unroll
        for (int m = 0; m < 4; ++m)
#pragma unroll
            for (int j = 0; j < 4; ++j) {
                int r = m * 16 + l4 * 4 + j;
                int ng = n0 + r;
                if (ng < N_NODES)
                    O[(size_t)ng * 128 + c] = f2bf(acc[m][n][j] + bb);
            }
    }
}

// ---------------------------------------------------------------------------
// attention logits for ONE t_src chunk (no atomics).
// att layout: att[(ts*E + e)*NH + h]
// ---------------------------------------------------------------------------
__global__ __launch_bounds__(256) void att_chunk_kernel(
    const u16* __restrict__ Qt, const u16* __restrict__ Kc,
    const int* __restrict__ ei_src, const int* __restrict__ ei_tar,
    float* __restrict__ att_chunk)
{
    int idx = blockIdx.x * 256 + threadIdx.x;
    if (idx >= E_PER_T * NH) return;
    int h = idx & 7;
    int e = idx >> 3;
    int src = ei_src[e];
    int tar = ei_tar[e];

    const uint4* qp = (const uint4*)(Qt + ((size_t)tar * HID + h * DK));
    const uint4* kp = (const uint4*)(Kc + ((size_t)src * HID + h * DK));
    uint4 q0 = qp[0], q1 = qp[1];
    uint4 k0 = kp[0], k1 = kp[1];
    float s = 0.f;
    const unsigned* pa = (const unsigned*)&q0;
    const unsigned* pb = (const unsigned*)&k0;
#pragma unroll
    for (int i = 0; i < 4; ++i) {
        s += __uint_as_float(pa[i] << 16) * __uint_as_float(pb[i] << 16)
           + __uint_as_float(pa[i] & 0xffff0000u) * __uint_as_float(pb[i] & 0xffff0000u);
    }
    pa = (const unsigned*)&q1; pb = (const unsigned*)&k1;
#pragma unroll
    for (int i = 0; i < 4; ++i) {
        s += __uint_as_float(pa[i] << 16) * __uint_as_float(pb[i] << 16)
           + __uint_as_float(pa[i] & 0xffff0000u) * __uint_as_float(pb[i] & 0xffff0000u);
    }
    att_chunk[idx] = s * 0.25f;  // / sqrt(16)
}

// ---------------------------------------------------------------------------
// stats gather: one wave per node. lane = j8*8 + h (8 edge slots x 8 heads).
// ---------------------------------------------------------------------------
__global__ __launch_bounds__(256) void stats_gather_kernel(
    const float* __restrict__ att, const int* __restrict__ offs,
    const int* __restrict__ eidbuf,
    float* __restrict__ m_c, float* __restrict__ m_n,
    float* __restrict__ s_c, float* __restrict__ s_s, int t_tar)
{
    const int lane = threadIdx.x & 63;
    const int wave = threadIdx.x >> 6;
    const int node = blockIdx.x * 4 + wave;
    if (node >= N_NODES) return;
    const int h  = lane & 7;
    const int j8 = lane >> 3;

    float mx = -1e30f, mn = 1e30f;
    for (int ts = 0; ts <= t_tar; ++ts) {
        int beg = offs[ts * (N_NODES + 1) + node];
        int end = offs[ts * (N_NODES + 1) + node + 1];
        for (int j = beg + j8; j < end; j += 8) {
            int e = eidbuf[ts * E_PER_T + j];
            float a = att[((size_t)ts * E_PER_T + e) * NH + h];
            mx = fmaxf(mx, a);
            mn = fminf(mn, a);
        }
    }
#pragma unroll
    for (int o = 8; o < 64; o <<= 1) {
        mx = fmaxf(mx, __shfl_xor(mx, o));
        mn = fminf(mn, __shfl_xor(mn, o));
    }

    float sc = 0.f, ss = 0.f;
    for (int ts = 0; ts <= t_tar; ++ts) {
        int beg = offs[ts * (N_NODES + 1) + node];
        int end = offs[ts * (N_NODES + 1) + node + 1];
        for (int j = beg + j8; j < end; j += 8) {
            int e = eidbuf[ts * E_PER_T + j];
            float a = att[((size_t)ts * E_PER_T + e) * NH + h];
            sc += __expf(a - mx);
            ss += __expf(mn - a);
        }
    }
#pragma unroll
    for (int o = 8; o < 64; o <<= 1) {
        sc += __shfl_xor(sc, o);
        ss += __shfl_xor(ss, o);
    }

    if (j8 == 0) {
        m_c[node * NH + h] = mx;
        m_n[node * NH + h] = mn;
        s_c[node * NH + h] = sc;
        s_s[node * NH + h] = ss;
    }
}

// ---------------------------------------------------------------------------
// agg gather for ONE chunk: one wave per node, lane owns dims {2l, 2l+1}.
// first=1 (ts==0 chunk) initializes the accumulators (init_hat fused away).
// ---------------------------------------------------------------------------
__global__ __launch_bounds__(256) void agg_gather_kernel(
    const float* __restrict__ att_chunk, const int* __restrict__ offs_ts,
    const int* __restrict__ eid_ts, const int* __restrict__ ei_src,
    const u16* __restrict__ Vc,
    const float* __restrict__ m_c, const float* __restrict__ m_n,
    const float* __restrict__ s_c, const float* __restrict__ s_s,
    float* __restrict__ hat_c, float* __restrict__ hat_s, int first)
{
    const int lane = threadIdx.x & 63;
    const int wave = threadIdx.x >> 6;
    const int node = blockIdx.x * 4 + wave;
    if (node >= N_NODES) return;

    const int beg = offs_ts[node];
    const int end = offs_ts[node + 1];
    if (!first && beg == end) return;

    const int h = lane >> 3;
    const int nh = node * NH + h;
    const float mc = m_c[nh];
    const float mn = m_n[nh];
    const float inv_sc = 1.f / (s_c[nh] + 1e-16f);
    const float inv_ss = 1.f / (s_s[nh] + 1e-16f);

    const size_t base = (size_t)node * HID + 2 * lane;
    float aC0, aC1, aS0, aS1;
    if (first) {
        aC0 = aC1 = aS0 = aS1 = 0.f;
    } else {
        aC0 = hat_c[base]; aC1 = hat_c[base + 1];
        aS0 = hat_s[base]; aS1 = hat_s[base + 1];
    }

    for (int j = beg; j < end; ++j) {
        int e = eid_ts[j];
        float a = att_chunk[(size_t)e * NH + h];
        float pc = __expf(a - mc) * inv_sc;
        float ps = __expf(mn - a) * inv_ss;
        int src = ei_src[e];
        unsigned v2 = *(const unsigned*)(Vc + (size_t)src * HID + 2 * lane);
        float v0 = __uint_as_float(v2 << 16);
        float v1 = __uint_as_float(v2 & 0xffff0000u);
        aC0 += v0 * pc; aC1 += v1 * pc;
        aS0 += v0 * ps; aS1 += v1 * ps;
    }
    hat_c[base] = aC0; hat_c[base + 1] = aC1;
    hat_s[base] = aS0; hat_s[base + 1] = aS1;
}

// ---------------------------------------------------------------------------
// FFN via MFMA: LN (VALU) -> bf16 A in swizzled LDS -> GEMM1 [64,128]@[128,256]
// -> fp32 GELU -> bf16 hid tile -> GEMM2 [64,256]@[256,128] -> h + r.
// Residual h stays fp32 (re-read from global). blockIdx.y = branch.
// ---------------------------------------------------------------------------
__global__ __launch_bounds__(256) void ffn_mfma_kernel(
    float* __restrict__ hat_c, float* __restrict__ hat_s,
    const float* __restrict__ x,
    const float* __restrict__ ln_s, const float* __restrict__ ln_b,
    const u16* __restrict__ W1T, const float* __restrict__ b1,
    const u16* __restrict__ W2T, const float* __restrict__ b2,
    int t_tar)
{
    __shared__ u16 hnS[64 * 128];    // 16 KB
    __shared__ u16 hidS[64 * 256];   // 32 KB
    const int br = blockIdx.y;
    float* __restrict__ hat = br ? hat_s : hat_c;
    const int n0 = blockIdx.x * 64;
    const int tid = threadIdx.x;
    const float* __restrict__ xt = x + (size_t)t_tar * N_NODES * 128;

    // ---- LayerNorm: 4 threads/row ----
    {
        const int row = tid >> 2, q = tid & 3;
        const int n = n0 + row;
        float v[32];
        float s = 0.f, s2 = 0.f;
        if (n < N_NODES) {
            const float4* hp = (const float4*)(hat + (size_t)n * 128 + q * 32);
            const float4* xp = (const float4*)(xt + (size_t)n * 128 + q * 32);
#pragma unroll
            for (int i = 0; i < 8; ++i) {
                float4 a = hp[i];
                if (br == 0) {
                    float4 bx = xp[i];
                    a.x += bx.x; a.y += bx.y; a.z += bx.z; a.w += bx.w;
                }
                v[4 * i] = a.x; v[4 * i + 1] = a.y;
                v[4 * i + 2] = a.z; v[4 * i + 3] = a.w;
                s  += a.x + a.y + a.z + a.w;
                s2 += a.x * a.x + a.y * a.y + a.z * a.z + a.w * a.w;
            }
        } else {
#pragma unroll
            for (int i = 0; i < 32; ++i) v[i] = 0.f;
        }
        s  += __shfl_xor(s, 1);  s  += __shfl_xor(s, 2);
        s2 += __shfl_xor(s2, 1); s2 += __shfl_xor(s2, 2);
        float mu  = s * (1.f / 128.f);
        float var = s2 * (1.f / 128.f) - mu * mu;
        float rstd = rsqrtf(var + 1e-5f);
        const int sbase = row * 128;
#pragma unroll
        for (int i = 0; i < 4; ++i) {
            uint4 uh; unsigned* ph = (unsigned*)&uh;
#pragma unroll
            for (int j = 0; j < 4; ++j) {
                int c0 = q * 32 + i * 8 + 2 * j;
                float h0 = (v[i * 8 + 2 * j]     - mu) * rstd * ln_s[c0]     + ln_b[c0];
                float h1 = (v[i * 8 + 2 * j + 1] - mu) * rstd * ln_s[c0 + 1] + ln_b[c0 + 1];
                if (n >= N_NODES) { h0 = 0.f; h1 = 0.f; }
                ph[j] = (unsigned)f2bf(h0) | ((unsigned)f2bf(h1) << 16);
            }
            int ch = (q * 4 + i) ^ (row & 15);
            *(uint4*)&hnS[sbase + ch * 8] = uh;
        }
    }
    __syncthreads();

    const int lane = tid & 63, w = tid >> 6;
    const int l15 = lane & 15, l4 = lane >> 4;
    const f32x4 z4 = {0.f, 0.f, 0.f, 0.f};

    // ---- GEMM1: wave w owns cols w*64..w*64+63 ----
    {
        f32x4 a1[4][4];
#pragma unroll
        for (int m = 0; m < 4; ++m)
#pragma unroll
            for (int n = 0; n < 4; ++n) a1[m][n] = z4;

#pragma unroll
        for (int ks = 0; ks < 4; ++ks) {
            const int ch = (ks * 4 + l4) ^ l15;
            bf16x8 af[4];
#pragma unroll
            for (int m = 0; m < 4; ++m)
                af[m] = *(const bf16x8*)&hnS[(m * 16 + l15) * 128 + ch * 8];
            bf16x8 bfr[4];
#pragma unroll
            for (int n = 0; n < 4; ++n)
                bfr[n] = *(const bf16x8*)(W1T + (size_t)(w * 64 + n * 16 + l15) * 128
                                              + ks * 32 + l4 * 8);
#pragma unroll
            for (int m = 0; m < 4; ++m)
#pragma unroll
                for (int n = 0; n < 4; ++n)
                    a1[m][n] = mfma16(af[m], bfr[n], a1[m][n]);
        }
        // bias + exact GELU, write swizzled bf16 hid tile
#pragma unroll
        for (int n = 0; n < 4; ++n) {
            int c = w * 64 + n * 16 + l15;
            float bb = b1[c];
#pragma unroll
            for (int m = 0; m < 4; ++m)
#pragma unroll
                for (int j = 0; j < 4; ++j) {
                    int r = m * 16 + l4 * 4 + j;
                    float zz = a1[m][n][j] + bb;
                    float g = 0.5f * zz * (1.f + erff(zz * 0.70710678118654752f));
                    hidS[r * 256 + (((c >> 3) ^ (r & 15)) * 8) + (c & 7)] = f2bf(g);
                }
        }
    }
    __syncthreads();

    // ---- GEMM2: wave w owns cols w*32..w*32+31 ----
    {
        f32x4 a2[4][2];
#pragma unroll
        for (int m = 0; m < 4; ++m)
#pragma unroll
            for (int n = 0; n < 2; ++n) a2[m][n] = z4;

#pragma unroll
        for (int ks = 0; ks < 8; ++ks) {
            const int ch = (ks * 4 + l4) ^ l15;
            bf16x8 af[4];
#pragma unroll
            for (int m = 0; m < 4; ++m)
                af[m] = *(const bf16x8*)&hidS[(m * 16 + l15) * 256 + ch * 8];
            bf16x8 bfr[2];
#pragma unroll
            for (int n = 0; n < 2; ++n)
                bfr[n] = *(const bf16x8*)(W2T + (size_t)(w * 32 + n * 16 + l15) * 256
                                              + ks * 32 + l4 * 8);
#pragma unroll
            for (int m = 0; m < 4; ++m)
#pragma unroll
                for (int n = 0; n < 2; ++n)
                    a2[m][n] = mfma16(af[m], bfr[n], a2[m][n]);
        }
        // epilogue: out = h + r (h fp32, re-read)
#pragma unroll
        for (int n = 0; n < 2; ++n) {
            int c = w * 32 + n * 16 + l15;
            float bb = b2[c];
#pragma unroll
            for (int m = 0; m < 4; ++m)
#pragma unroll
                for (int j = 0; j < 4; ++j) {
                    int r = m * 16 + l4 * 4 + j;
                    int ng = n0 + r;
                    if (ng < N_NODES) {
                        size_t idx = (size_t)ng * 128 + c;
                        float h = hat[idx];
                        if (br == 0) h += xt[idx];
                        hat[idx] = h + a2[m][n][j] + bb;
                    }
                }
        }
    }
}

// ---------------------------------------------------------------------------
// pack outputs: out[0]=c+s, out[1]=c, out[2]=s  ([3][T][1][N][128] fp32)
// ---------------------------------------------------------------------------
__global__ __launch_bounds__(256) void combine_kernel(
    const float* __restrict__ hat_c, const float* __restrict__ hat_s,
    float* __restrict__ out, int t_tar)
{
    size_t i = (size_t)blockIdx.x * 256 + threadIdx.x;
    if (i >= (size_t)N_NODES * HID) return;
    float c = hat_c[i], s = hat_s[i];
    const size_t TS = (size_t)T_WIN * N_NODES * HID;
    size_t o = (size_t)t_tar * N_NODES * HID + i;
    out[o]          = c + s;
    out[TS + o]     = c;
    out[2 * TS + o] = s;
}

extern "C" void kernel_launch(void* const* d_in, const int* in_sizes, int n_in,
                              void* d_out, int out_size, void* d_ws, size_t ws_size,
                              hipStream_t stream) {
    const float* x    = (const float*)d_in[0];
    const int*   ei   = (const int*)  d_in[1];
    const float* Wq   = (const float*)d_in[2];
    const float* bq   = (const float*)d_in[3];
    const float* Wk   = (const float*)d_in[4];
    const float* bk   = (const float*)d_in[5];
    const float* Wv   = (const float*)d_in[6];
    const float* bv   = (const float*)d_in[7];
    const float* ln_s = (const float*)d_in[8];
    const float* ln_b = (const float*)d_in[9];
    const float* W1   = (const float*)d_in[10];
    const float* b1   = (const float*)d_in[11];
    const float* W2   = (const float*)d_in[12];
    const float* b2   = (const float*)d_in[13];
    float* out = (float*)d_out;

    // ---- Workspace layout ----
    const size_t NHID = (size_t)N_NODES * HID;  // 6,400,000
    char* p = (char*)d_ws;
    auto alloc = [&p](size_t bytes) -> void* {
        void* r = (void*)p;
        p += (bytes + 255) & ~(size_t)255;
        return r;
    };
    float* hat_c = (float*)alloc(NHID * 4);
    float* hat_s = (float*)alloc(NHID * 4);
    float* att   = (float*)alloc((size_t)T_WIN * E_PER_T * NH * 4);
    float* m_c   = (float*)alloc((size_t)N_NODES * NH * 4);
    float* m_n   = (float*)alloc((size_t)N_NODES * NH * 4);
    float* s_c   = (float*)alloc((size_t)N_NODES * NH * 4);
    float* s_s   = (float*)alloc((size_t)N_NODES * NH * 4);
    int* offs    = (int*)alloc((size_t)T_WIN * (N_NODES + 1) * 4);
    int* cursor  = (int*)alloc((size_t)T_WIN * N_NODES * 4);
    int* eidbuf  = (int*)alloc((size_t)T_WIN * E_PER_T * 4);
    u16* WqTh = (u16*)alloc(128 * 128 * 2);
    u16* WqTl = (u16*)alloc(128 * 128 * 2);
    u16* WkTh = (u16*)alloc(128 * 128 * 2);
    u16* WkTl = (u16*)alloc(128 * 128 * 2);
    u16* WvTh = (u16*)alloc(128 * 128 * 2);
    u16* WvTl = (u16*)alloc(128 * 128 * 2);
    u16* W1T  = (u16*)alloc(128 * 256 * 2);
    u16* W2T  = (u16*)alloc(256 * 128 * 2);
    u16* Qt   = (u16*)alloc(NHID * 2);

    // cached K/V path if workspace permits (+76.8 MB), else per-t recompute
    size_t used = (size_t)(p - (char*)d_ws);
    bool cached = ws_size >= used + 6 * NHID * 2 + 4096;
    u16 *Kall = nullptr, *Vall = nullptr, *KV = nullptr;
    if (cached) {
        Kall = (u16*)alloc(3 * NHID * 2);
        Vall = (u16*)alloc(3 * NHID * 2);
    } else {
        KV = (u16*)alloc(NHID * 2);
    }

    const int PROJ_BLOCKS = (N_NODES + 63) / 64;          // 782
    const int EDGE_BLOCKS = (E_PER_T * NH + 255) / 256;   // 3125
    const int NODE_BLOCKS = (N_NODES + 3) / 4;            // 12500
    const int TN_BLOCKS   = (T_WIN * N_NODES + 255) / 256;
    const int TE_BLOCKS   = (T_WIN * E_PER_T + 255) / 256;

    // ---- weight prep ----
    wsplit_kernel<<<64, 256, 0, stream>>>(Wq, WqTh, WqTl, 128, 128);
    wsplit_kernel<<<64, 256, 0, stream>>>(Wk, WkTh, WkTl, 128, 128);
    wsplit_kernel<<<64, 256, 0, stream>>>(Wv, WvTh, WvTl, 128, 128);
    wt_kernel<<<128, 256, 0, stream>>>(W1, W1T, 128, 256);
    wt_kernel<<<128, 256, 0, stream>>>(W2, W2T, 256, 128);

    // ---- CSR build ----
    zero_counts_kernel<<<TN_BLOCKS, 256, 0, stream>>>(cursor);
    hist_kernel<<<TE_BLOCKS, 256, 0, stream>>>(ei, cursor);
    scan_kernel<<<T_WIN, 1024, 0, stream>>>(cursor, offs);
    copy_cursor_kernel<<<TN_BLOCKS, 256, 0, stream>>>(offs, cursor);
    fill_kernel<<<TE_BLOCKS, 256, 0, stream>>>(ei, cursor, eidbuf);

    if (cached) {
        for (int ts = 0; ts < T_WIN; ++ts) {
            project_mfma_kernel<<<PROJ_BLOCKS, 256, 0, stream>>>(
                x + (size_t)ts * NHID, WkTh, WkTl, bk, Kall + (size_t)ts * NHID);
            project_mfma_kernel<<<PROJ_BLOCKS, 256, 0, stream>>>(
                x + (size_t)ts * NHID, WvTh, WvTl, bv, Vall + (size_t)ts * NHID);
        }
    }

    for (int t = 0; t < T_WIN; ++t) {
        project_mfma_kernel<<<PROJ_BLOCKS, 256, 0, stream>>>(
            x + (size_t)t * NHID, WqTh, WqTl, bq, Qt);

        // attention logits per source timestep
        for (int ts = 0; ts <= t; ++ts) {
            const u16* Kc;
            if (cached) {
                Kc = Kall + (size_t)ts * NHID;
            } else {
                project_mfma_kernel<<<PROJ_BLOCKS, 256, 0, stream>>>(
                    x + (size_t)ts * NHID, WkTh, WkTl, bk, KV);
                Kc = KV;
            }
            att_chunk_kernel<<<EDGE_BLOCKS, 256, 0, stream>>>(
                Qt, Kc,
                ei + (size_t)(ts * 2) * E_PER_T,
                ei + (size_t)(ts * 2 + 1) * E_PER_T,
                att + (size_t)ts * E_PER_T * NH);
        }

        stats_gather_kernel<<<NODE_BLOCKS, 256, 0, stream>>>(
            att, offs, eidbuf, m_c, m_n, s_c, s_s, t);

        // aggregation per source timestep (ts==0 initializes hat)
        for (int ts = 0; ts <= t; ++ts) {
            const u16* Vc;
            if (cached) {
                Vc = Vall + (size_t)ts * NHID;
            } else {
                project_mfma_kernel<<<PROJ_BLOCKS, 256, 0, stream>>>(
                    x + (size_t)ts * NHID, WvTh, WvTl, bv, KV);
                Vc = KV;
            }
            agg_gather_kernel<<<NODE_BLOCKS, 256, 0, stream>>>(
                att + (size_t)ts * E_PER_T * NH,
                offs + ts * (N_NODES + 1),
                eidbuf + ts * E_PER_T,
                ei + (size_t)(ts * 2) * E_PER_T,
                Vc, m_c, m_n, s_c, s_s, hat_c, hat_s, (ts == 0) ? 1 : 0);
        }

        dim3 fg(PROJ_BLOCKS, 2);
        ffn_mfma_kernel<<<fg, 256, 0, stream>>>(
            hat_c, hat_s, x, ln_s, ln_b, W1T, b1, W2T, b2, t);
        combine_kernel<<<((int)NHID + 255) / 256, 256, 0, stream>>>(hat_c, hat_s, out, t);
    }
}